// Round 6
// baseline (205.858 us; speedup 1.0000x reference)
//
#include <hip/hip_runtime.h>
#include <math.h>

#define HID 512
#define KP 520              // padded k-row (+8 fp16 = 16B): conflict-spread b128 groups
#define PPB 16              // points per block (= MFMA n-dim)

typedef __attribute__((ext_vector_type(8))) _Float16 half8;   // 4 VGPRs, MFMA frag
typedef __attribute__((ext_vector_type(4))) _Float16 half4;
typedef __attribute__((ext_vector_type(4))) float f32x4;

static __device__ __forceinline__ float fast_tanh(float x) {
    float e = __expf(2.f * x);
    return 1.f - 2.f / (e + 1.f);
}

// ---------------------------------------------------------------------------
// W prep: single fp16 plane, slab layout for fully-coalesced frag loads:
//   Wh[jb(32)][kb(16)][l15(16)][quad(4)][k8(8)] ; j = jb*16+l15, k = kb*32+quad*8+k8
// Each (jb,kb) slab = 512 elems = 1 KB contiguous = one wave b128 load.
// One launch preps both layers: blockIdx.x >= 1024 -> W2.
// ---------------------------------------------------------------------------
__global__ __launch_bounds__(256) void prep_wt(
    const float* __restrict__ W1, const float* __restrict__ W2,
    _Float16* __restrict__ W1h, _Float16* __restrict__ W2h)
{
    int b = blockIdx.x;
    const float* W = (b < 1024) ? W1 : W2;
    _Float16* Wh   = (b < 1024) ? W1h : W2h;
    int gid = (b & 1023) * 256 + threadIdx.x;    // output-linear
    int k8   = gid & 7;
    int quad = (gid >> 3) & 3;
    int l15  = (gid >> 5) & 15;
    int kb   = (gid >> 9) & 15;
    int jb   = gid >> 13;
    int j = jb * 16 + l15;
    int k = kb * 32 + quad * 8 + k8;
    Wh[gid] = (_Float16)W[k * HID + j];
}

// ---------------------------------------------------------------------------
// One hidden-layer pass. A (B-op) in LDS Als[s][p][k]; W (A-op) streamed from
// L2 in 1KB slabs with ping-pong register prefetch. Wave wv owns j in
// [128*wv, 128*wv+128) (8 slabs of 16 j); one p-frag (p = l15); 4 states.
// z = Wh*A (single-term fp16; W rounding ~2^-11 relative, random-signed).
// FULL: emit h,t1,t2,S planes; else only h,S.
// ---------------------------------------------------------------------------
template<bool FULL>
static __device__ __forceinline__ void layer_pass(
    const _Float16* __restrict__ Wh, const float* __restrict__ bias,
    _Float16 (*Als)[PPB][KP], int wv, int lane)
{
    const int l15 = lane & 15, quad = lane >> 4;
    const int j0w = wv * 128;
    const int jb0 = wv * 8;                 // first 16-j slab group
    const int foff = l15 * 32 + quad * 8;   // lane offset within 1KB slab

    f32x4 acc[4][8];                        // [state][jt]
    #pragma unroll
    for (int s = 0; s < 4; ++s)
        #pragma unroll
        for (int jt = 0; jt < 8; ++jt) acc[s][jt] = (f32x4)0.f;

    half8 wA[8], wB[8];
    #pragma unroll
    for (int jt = 0; jt < 8; ++jt)
        wA[jt] = *(const half8*)(Wh + (size_t)((jb0 + jt) * 16) * 512 + foff);

    auto iter = [&](int kb, half8 (&wc)[8], half8 (&wn)[8]) {
        half8 a[4];
        #pragma unroll
        for (int s = 0; s < 4; ++s)
            a[s] = *(const half8*)&Als[s][l15][kb * 32 + quad * 8];
        if (kb < 15) {
            #pragma unroll
            for (int jt = 0; jt < 8; ++jt)
                wn[jt] = *(const half8*)(Wh + (size_t)((jb0 + jt) * 16 + kb + 1) * 512 + foff);
        }
        #pragma unroll
        for (int s = 0; s < 4; ++s)
            #pragma unroll
            for (int jt = 0; jt < 8; ++jt)
                acc[s][jt] = __builtin_amdgcn_mfma_f32_16x16x32_f16(
                    wc[jt], a[s], acc[s][jt], 0, 0, 0);
    };

    #pragma unroll
    for (int kb = 0; kb < 16; kb += 2) {
        iter(kb,     wA, wB);
        iter(kb + 1, wB, wA);
    }

    __syncthreads();   // all waves done reading Als; safe to overwrite

    // epilogue: D row m = jt*16+quad*4+r (j-offset), col n = p = l15
    #pragma unroll
    for (int jt = 0; jt < 8; ++jt) {
        const int jbase = j0w + jt * 16 + quad * 4;
        f32x4 bv = *(const f32x4*)&bias[jbase];
        half4 vh, vt1, vt2, vS;
        #pragma unroll
        for (int r = 0; r < 4; ++r) {
            float a  = fast_tanh(acc[0][jt][r] + bv[r]);
            float g  = 1.f - a * a;
            float z1 = acc[1][jt][r];
            float z2 = acc[2][jt][r];
            vh[r] = (_Float16)a;
            if (FULL) {
                vt1[r] = (_Float16)(g * z1);
                vt2[r] = (_Float16)(g * z2);
            }
            vS[r] = (_Float16)(g * acc[3][jt][r] - 2.f * a * g * (z1 * z1 + z2 * z2));
        }
        *(half4*)&Als[0][l15][jbase] = vh;
        if (FULL) {
            *(half4*)&Als[1][l15][jbase] = vt1;
            *(half4*)&Als[2][l15][jbase] = vt2;
        }
        *(half4*)&Als[3][l15][jbase] = vS;
    }
    __syncthreads();   // Als(next layer) complete
}

// ---------------------------------------------------------------------------
// Fused: layer0 init -> L1 -> L2 -> final dot + loss partials.
// 16 pts/block, 256 threads (4 waves), 2 blocks/CU.
// ---------------------------------------------------------------------------
__global__ __launch_bounds__(256, 2) void pois_fused(
    const float* __restrict__ x_int, const float* __restrict__ x_bnd,
    const float* __restrict__ W0, const float* __restrict__ b0,
    const _Float16* __restrict__ W1h, const float* __restrict__ b1,
    const _Float16* __restrict__ W2h, const float* __restrict__ b2,
    const float* __restrict__ W3, const float* __restrict__ b3,
    float* __restrict__ partials, int NI, int NT, int nblk)
{
    __shared__ _Float16 Als[4][PPB][KP];     // [state][p][k], 65 KB
    __shared__ float sc[32];

    const int tid = threadIdx.x;
    const int wv = tid >> 6, lane = tid & 63;
    const int p0 = blockIdx.x * PPB;

    // ---- layer 0: thread (p = tid&15, kc = tid>>4) covers 32 k ----
    {
        const int p = tid & 15, kc = tid >> 4;
        int gp = p0 + p;
        int gpc = (gp >= NT) ? 0 : gp;
        float xx, yy;
        if (gpc < NI) { xx = x_int[2 * gpc];        yy = x_int[2 * gpc + 1]; }
        else          { xx = x_bnd[2 * (gpc - NI)]; yy = x_bnd[2 * (gpc - NI) + 1]; }
        #pragma unroll
        for (int k8 = 0; k8 < 4; ++k8) {
            const int k = kc * 32 + k8 * 8;
            f32x4 w0a = *(const f32x4*)&W0[k],       w0b = *(const f32x4*)&W0[k + 4];
            f32x4 w1a = *(const f32x4*)&W0[HID + k], w1b = *(const f32x4*)&W0[HID + k + 4];
            f32x4 b0a = *(const f32x4*)&b0[k],       b0b = *(const f32x4*)&b0[k + 4];
            half8 vh, vt1, vt2, vS;
            #pragma unroll
            for (int i = 0; i < 8; ++i) {
                float w0i = (i < 4) ? w0a[i] : w0b[i - 4];
                float w1i = (i < 4) ? w1a[i] : w1b[i - 4];
                float bbi = (i < 4) ? b0a[i] : b0b[i - 4];
                float a = fast_tanh(xx * w0i + yy * w1i + bbi);
                float g = 1.f - a * a;
                vh[i]  = (_Float16)a;
                vt1[i] = (_Float16)(g * w0i);
                vt2[i] = (_Float16)(g * w1i);
                vS[i]  = (_Float16)(-2.f * a * g * (w0i * w0i + w1i * w1i));
            }
            *(half8*)&Als[0][p][k] = vh;
            *(half8*)&Als[1][p][k] = vt1;
            *(half8*)&Als[2][p][k] = vt2;
            *(half8*)&Als[3][p][k] = vS;
        }
    }
    __syncthreads();

    layer_pass<true >(W1h, b1, Als, wv, lane);
    layer_pass<false>(W2h, b2, Als, wv, lane);

    // ---- final: u = h.W3 + b3 ; lap = S.W3 ; loss partials ----
    {
        const int psub = lane >> 4, kc = lane & 15;
        const int p = wv * 4 + psub;
        float u = 0.f, lap = 0.f;
        #pragma unroll
        for (int k8 = 0; k8 < 4; ++k8) {
            const int k = kc * 32 + k8 * 8;
            half8 hh = *(const half8*)&Als[0][p][k];
            half8 ss = *(const half8*)&Als[3][p][k];
            f32x4 wa = *(const f32x4*)&W3[k], wb = *(const f32x4*)&W3[k + 4];
            #pragma unroll
            for (int i = 0; i < 8; ++i) {
                float w = (i < 4) ? wa[i] : wb[i - 4];
                u   += (float)hh[i] * w;
                lap += (float)ss[i] * w;
            }
        }
        #pragma unroll
        for (int off = 1; off < 16; off <<= 1) {
            u   += __shfl_xor(u, off);
            lap += __shfl_xor(lap, off);
        }
        if (kc == 0) {
            int gp = p0 + p;
            float vi = 0.f, vb = 0.f;
            if (gp < NI) {
                const float PIf = 3.14159265358979323846f;
                float xx = x_int[2 * gp], yy = x_int[2 * gp + 1];
                float sx = sinf(PIf * xx);
                float y2 = yy * yy;
                float sy = sinf(PIf * y2), cy = cosf(PIf * y2);
                float f = -PIf * PIf * (1.f + 4.f * y2) * sx * sy + 2.f * PIf * sx * cy;
                float r = lap - f;
                vi = r * r;
            } else if (gp < NT) {
                float uu = u + b3[0];
                vb = uu * uu;
            }
            sc[p * 2] = vi; sc[p * 2 + 1] = vb;
        }
    }
    __syncthreads();
    if (tid == 0) {
        float svi = 0.f, svb = 0.f;
        #pragma unroll
        for (int p = 0; p < PPB; ++p) { svi += sc[p * 2]; svb += sc[p * 2 + 1]; }
        partials[blockIdx.x] = svi;
        partials[nblk + blockIdx.x] = svb;
    }
}

// ---------------------------------------------------------------------------
// Deterministic final reduction (no atomics)
// ---------------------------------------------------------------------------
__global__ __launch_bounds__(256) void pois_reduce(
    const float* __restrict__ partials, float* __restrict__ out,
    int nblk, int NI, int NB)
{
    int tid = threadIdx.x;
    float si = 0.f, sb = 0.f;
    for (int i = tid; i < nblk; i += 256) {
        si += partials[i];
        sb += partials[nblk + i];
    }
    #pragma unroll
    for (int off = 32; off > 0; off >>= 1) {
        si += __shfl_xor(si, off);
        sb += __shfl_xor(sb, off);
    }
    __shared__ float ri[4], rb[4];
    int wv = tid >> 6;
    if ((tid & 63) == 0) { ri[wv] = si; rb[wv] = sb; }
    __syncthreads();
    if (tid == 0) {
        float inter = (ri[0] + ri[1] + ri[2] + ri[3]) / (float)NI;
        float bound = (rb[0] + rb[1] + rb[2] + rb[3]) / (float)NB;
        out[0] = 0.01f * inter + bound;   // ALPHA = 0.01
        out[1] = inter;
        out[2] = bound;
    }
}

// ---------------------------------------------------------------------------
extern "C" void kernel_launch(void* const* d_in, const int* in_sizes, int n_in,
                              void* d_out, int out_size, void* d_ws, size_t ws_size,
                              hipStream_t stream)
{
    const float* x_int = (const float*)d_in[0];
    const float* x_bnd = (const float*)d_in[1];
    const float* W0 = (const float*)d_in[2];
    const float* b0 = (const float*)d_in[3];
    const float* W1 = (const float*)d_in[4];
    const float* b1 = (const float*)d_in[5];
    const float* W2 = (const float*)d_in[6];
    const float* b2 = (const float*)d_in[7];
    const float* W3 = (const float*)d_in[8];
    const float* b3 = (const float*)d_in[9];

    int NI = in_sizes[0] / 2;    // 20000
    int NB = in_sizes[1] / 2;    // 800
    int NT = NI + NB;            // 20800
    int nblk = (NT + PPB - 1) / PPB;   // 1300

    // ws: [partials 16KB][W1h 512KB][W2h 512KB]
    float* partials = (float*)d_ws;
    _Float16* W1h = (_Float16*)((char*)d_ws + 16384);
    _Float16* W2h = W1h + 262144;

    prep_wt<<<2048, 256, 0, stream>>>(W1, W2, W1h, W2h);

    pois_fused<<<nblk, 256, 0, stream>>>(
        x_int, x_bnd, W0, b0, W1h, b1, W2h, b2, W3, b3,
        partials, NI, NT, nblk);

    pois_reduce<<<1, 256, 0, stream>>>(partials, (float*)d_out, nblk, NI, NB);
}

// Round 7
// 193.700 us; speedup vs baseline: 1.0628x; 1.0628x over previous
//
#include <hip/hip_runtime.h>
#include <math.h>

#define HID 512
#define PPB 16              // points per block (= MFMA n-dim)
#define SLAB 512            // halfs per (state,kb) slab: 16 p x 32 k, 1 KB

typedef __attribute__((ext_vector_type(8))) _Float16 half8;   // 4 VGPRs, MFMA frag
typedef __attribute__((ext_vector_type(4))) _Float16 half4;
typedef __attribute__((ext_vector_type(4))) float f32x4;

static __device__ __forceinline__ float fast_tanh(float x) {
    float e = __expf(2.f * x);
    return 1.f - 2.f / (e + 1.f);
}

// ---------------------------------------------------------------------------
// W prep: LDS-tiled transpose + fp16 cast into slab layout
//   Wh[(jb*16 + kb)*512 + l15*32 + quad*8 + k8], j = jb*16+l15, k = kb*32+quad*8+k8
// Each (jb,kb) slab = 1 KB contiguous = one conflict-free wave b128 access.
// Grid: 128 blocks (2 matrices x 8 jtiles x 8 ktiles of 64x64).
// ---------------------------------------------------------------------------
__global__ __launch_bounds__(256) void prep_wt(
    const float* __restrict__ W1, const float* __restrict__ W2,
    _Float16* __restrict__ W1h, _Float16* __restrict__ W2h)
{
    __shared__ float T[64][65];
    int b = blockIdx.x;
    const float* W = (b < 64) ? W1 : W2;
    _Float16* Wh   = (b < 64) ? W1h : W2h;
    int tb = b & 63;
    int jbG = tb >> 3, kbG = tb & 7;
    int j0 = jbG * 64, k0 = kbG * 64;
    int t = threadIdx.x;
    #pragma unroll
    for (int r = 0; r < 16; ++r) {
        int kl = r * 4 + (t >> 6);
        int jl = t & 63;
        T[kl][jl] = W[(size_t)(k0 + kl) * HID + j0 + jl];   // coalesced
    }
    __syncthreads();
    int ljb = t >> 6, l15 = (t >> 2) & 15, quad = t & 3;
    #pragma unroll
    for (int lkb = 0; lkb < 2; ++lkb) {
        half8 v;
        #pragma unroll
        for (int k8 = 0; k8 < 8; ++k8)
            v[k8] = (_Float16)T[lkb * 32 + quad * 8 + k8][ljb * 16 + l15];
        size_t out = (size_t)((jbG * 4 + ljb) * 16 + (kbG * 2 + lkb)) * SLAB
                   + l15 * 32 + quad * 8;
        *(half8*)(Wh + out) = v;                            // coalesced 1KB/wave
    }
}

// ---------------------------------------------------------------------------
// One hidden-layer pass. A (B-op) in LDS slabs; W (A-op) streamed from L2
// with ping-pong register prefetch. Wave wv owns j in [64*wv, 64*wv+64)
// (4 slabs of 16 j); p-frag = l15; 4 states. acc = 64 regs, W regs = 32.
// FULL: emit h,t1,t2,S planes; else only h,S.
// ---------------------------------------------------------------------------
template<bool FULL>
static __device__ __forceinline__ void layer_pass(
    const _Float16* __restrict__ Wh, const float* __restrict__ bias,
    _Float16* Als, int wv, int lane)
{
    const int l15 = lane & 15, quad = lane >> 4;
    const int j0w = wv * 64;
    const int jb0 = wv * 4;                 // first 16-j slab index
    const int loff = l15 * 32 + quad * 8;   // within-slab offset (halfs)

    f32x4 acc[4][4];                        // [state][jt]
    #pragma unroll
    for (int s = 0; s < 4; ++s)
        #pragma unroll
        for (int jt = 0; jt < 4; ++jt) acc[s][jt] = (f32x4)0.f;

    half8 wA[4], wB[4];
    #pragma unroll
    for (int jt = 0; jt < 4; ++jt)
        wA[jt] = *(const half8*)(Wh + (size_t)((jb0 + jt) * 16) * SLAB + loff);

    auto iter = [&](int kb, half8 (&wc)[4], half8 (&wn)[4]) {
        half8 a[4];
        #pragma unroll
        for (int s = 0; s < 4; ++s)
            a[s] = *(const half8*)(Als + (s * 16 + kb) * SLAB + loff);
        if (kb < 15) {
            #pragma unroll
            for (int jt = 0; jt < 4; ++jt)
                wn[jt] = *(const half8*)(Wh + (size_t)((jb0 + jt) * 16 + kb + 1) * SLAB + loff);
        }
        #pragma unroll
        for (int s = 0; s < 4; ++s)
            #pragma unroll
            for (int jt = 0; jt < 4; ++jt)
                acc[s][jt] = __builtin_amdgcn_mfma_f32_16x16x32_f16(
                    wc[jt], a[s], acc[s][jt], 0, 0, 0);
    };

    #pragma unroll
    for (int kb = 0; kb < 16; kb += 2) {
        iter(kb,     wA, wB);
        iter(kb + 1, wB, wA);
    }

    __syncthreads();   // all waves done reading Als; safe to overwrite

    // epilogue: D row m = jt*16+quad*4+r (j-offset), col n = p = l15
    #pragma unroll
    for (int jt = 0; jt < 4; ++jt) {
        const int jbase = j0w + jt * 16 + quad * 4;
        f32x4 bv = *(const f32x4*)&bias[jbase];
        half4 vh, vt1, vt2, vS;
        #pragma unroll
        for (int r = 0; r < 4; ++r) {
            float a  = fast_tanh(acc[0][jt][r] + bv[r]);
            float g  = 1.f - a * a;
            float z1 = acc[1][jt][r];
            float z2 = acc[2][jt][r];
            vh[r] = (_Float16)a;
            if (FULL) {
                vt1[r] = (_Float16)(g * z1);
                vt2[r] = (_Float16)(g * z2);
            }
            vS[r] = (_Float16)(g * acc[3][jt][r] - 2.f * a * g * (z1 * z1 + z2 * z2));
        }
        const int okb = jbase >> 5;                 // next-layer k-slab
        const int ooff = l15 * 32 + (jbase & 31);   // point row = l15
        *(half4*)(Als + (0 * 16 + okb) * SLAB + ooff) = vh;
        if (FULL) {
            *(half4*)(Als + (1 * 16 + okb) * SLAB + ooff) = vt1;
            *(half4*)(Als + (2 * 16 + okb) * SLAB + ooff) = vt2;
        }
        *(half4*)(Als + (3 * 16 + okb) * SLAB + ooff) = vS;
    }
    __syncthreads();   // Als(next layer) complete
}

// ---------------------------------------------------------------------------
// Fused: layer0 init -> L1 -> L2 -> final dot + loss partials.
// 16 pts/block, 512 threads (8 waves), 2 blocks/CU -> 4 waves/SIMD.
// ---------------------------------------------------------------------------
__global__ __launch_bounds__(512, 4) void pois_fused(
    const float* __restrict__ x_int, const float* __restrict__ x_bnd,
    const float* __restrict__ W0, const float* __restrict__ b0,
    const _Float16* __restrict__ W1h, const float* __restrict__ b1,
    const _Float16* __restrict__ W2h, const float* __restrict__ b2,
    const float* __restrict__ W3, const float* __restrict__ b3,
    float* __restrict__ partials, int NI, int NT, int nblk)
{
    __shared__ _Float16 Als[4 * 16 * SLAB];   // 64 KB: [s][kb] 1KB slabs
    __shared__ float sc[32];

    const int tid = threadIdx.x;
    const int wv = tid >> 6, lane = tid & 63;
    const int p0 = blockIdx.x * PPB;

    // ---- layer 0: wave wv covers kb in {2wv, 2wv+1}; lane = (p<<2)|quad ----
    {
        const int p = lane >> 2, quad = lane & 3;
        int gp = p0 + p;
        int gpc = (gp >= NT) ? 0 : gp;
        float xx, yy;
        if (gpc < NI) { xx = x_int[2 * gpc];        yy = x_int[2 * gpc + 1]; }
        else          { xx = x_bnd[2 * (gpc - NI)]; yy = x_bnd[2 * (gpc - NI) + 1]; }
        #pragma unroll
        for (int i = 0; i < 2; ++i) {
            const int kb = wv * 2 + i;
            const int k = kb * 32 + quad * 8;
            f32x4 w0a = *(const f32x4*)&W0[k],       w0b = *(const f32x4*)&W0[k + 4];
            f32x4 w1a = *(const f32x4*)&W0[HID + k], w1b = *(const f32x4*)&W0[HID + k + 4];
            f32x4 b0a = *(const f32x4*)&b0[k],       b0b = *(const f32x4*)&b0[k + 4];
            half8 vh, vt1, vt2, vS;
            #pragma unroll
            for (int e = 0; e < 8; ++e) {
                float w0i = (e < 4) ? w0a[e] : w0b[e - 4];
                float w1i = (e < 4) ? w1a[e] : w1b[e - 4];
                float bbi = (e < 4) ? b0a[e] : b0b[e - 4];
                float a = fast_tanh(xx * w0i + yy * w1i + bbi);
                float g = 1.f - a * a;
                vh[e]  = (_Float16)a;
                vt1[e] = (_Float16)(g * w0i);
                vt2[e] = (_Float16)(g * w1i);
                vS[e]  = (_Float16)(-2.f * a * g * (w0i * w0i + w1i * w1i));
            }
            const int off = p * 32 + quad * 8;      // lane*16 B: contiguous
            *(half8*)(Als + (0 * 16 + kb) * SLAB + off) = vh;
            *(half8*)(Als + (1 * 16 + kb) * SLAB + off) = vt1;
            *(half8*)(Als + (2 * 16 + kb) * SLAB + off) = vt2;
            *(half8*)(Als + (3 * 16 + kb) * SLAB + off) = vS;
        }
    }
    __syncthreads();

    layer_pass<true >(W1h, b1, Als, wv, lane);
    layer_pass<false>(W2h, b2, Als, wv, lane);

    // ---- final: u = h.W3 + b3 ; lap = S.W3 ; loss partials ----
    {
        const int hl = lane >> 5, l5 = lane & 31;
        const int p = wv * 2 + hl;                 // 8 waves x 2 = 16 points
        const int kb = l5 >> 1;
        const int off = p * 32 + (l5 & 1) * 16;
        half8 h0 = *(const half8*)(Als + (0 * 16 + kb) * SLAB + off);
        half8 h1 = *(const half8*)(Als + (0 * 16 + kb) * SLAB + off + 8);
        half8 s0 = *(const half8*)(Als + (3 * 16 + kb) * SLAB + off);
        half8 s1 = *(const half8*)(Als + (3 * 16 + kb) * SLAB + off + 8);
        const int k0 = l5 * 16;
        f32x4 wa = *(const f32x4*)&W3[k0],     wb = *(const f32x4*)&W3[k0 + 4];
        f32x4 wc = *(const f32x4*)&W3[k0 + 8], wd = *(const f32x4*)&W3[k0 + 12];
        float u = 0.f, lap = 0.f;
        #pragma unroll
        for (int e = 0; e < 4; ++e) {
            u   += (float)h0[e] * wa[e] + (float)h0[e + 4] * wb[e]
                 + (float)h1[e] * wc[e] + (float)h1[e + 4] * wd[e];
            lap += (float)s0[e] * wa[e] + (float)s0[e + 4] * wb[e]
                 + (float)s1[e] * wc[e] + (float)s1[e + 4] * wd[e];
        }
        #pragma unroll
        for (int off2 = 1; off2 < 32; off2 <<= 1) {   // stays within 32-half
            u   += __shfl_xor(u, off2);
            lap += __shfl_xor(lap, off2);
        }
        if (l5 == 0) {
            int gp = p0 + p;
            float vi = 0.f, vb = 0.f;
            if (gp < NI) {
                const float PIf = 3.14159265358979323846f;
                float xx = x_int[2 * gp], yy = x_int[2 * gp + 1];
                float sx = sinf(PIf * xx);
                float y2 = yy * yy;
                float sy = sinf(PIf * y2), cy = cosf(PIf * y2);
                float f = -PIf * PIf * (1.f + 4.f * y2) * sx * sy + 2.f * PIf * sx * cy;
                float r = lap - f;
                vi = r * r;
            } else if (gp < NT) {
                float uu = u + b3[0];
                vb = uu * uu;
            }
            sc[p * 2] = vi; sc[p * 2 + 1] = vb;
        }
    }
    __syncthreads();
    if (tid == 0) {
        float svi = 0.f, svb = 0.f;
        #pragma unroll
        for (int p = 0; p < PPB; ++p) { svi += sc[p * 2]; svb += sc[p * 2 + 1]; }
        partials[blockIdx.x] = svi;
        partials[nblk + blockIdx.x] = svb;
    }
}

// ---------------------------------------------------------------------------
// Deterministic final reduction (no atomics)
// ---------------------------------------------------------------------------
__global__ __launch_bounds__(256) void pois_reduce(
    const float* __restrict__ partials, float* __restrict__ out,
    int nblk, int NI, int NB)
{
    int tid = threadIdx.x;
    float si = 0.f, sb = 0.f;
    for (int i = tid; i < nblk; i += 256) {
        si += partials[i];
        sb += partials[nblk + i];
    }
    #pragma unroll
    for (int off = 32; off > 0; off >>= 1) {
        si += __shfl_xor(si, off);
        sb += __shfl_xor(sb, off);
    }
    __shared__ float ri[4], rb[4];
    int wv = tid >> 6;
    if ((tid & 63) == 0) { ri[wv] = si; rb[wv] = sb; }
    __syncthreads();
    if (tid == 0) {
        float inter = (ri[0] + ri[1] + ri[2] + ri[3]) / (float)NI;
        float bound = (rb[0] + rb[1] + rb[2] + rb[3]) / (float)NB;
        out[0] = 0.01f * inter + bound;   // ALPHA = 0.01
        out[1] = inter;
        out[2] = bound;
    }
}

// ---------------------------------------------------------------------------
extern "C" void kernel_launch(void* const* d_in, const int* in_sizes, int n_in,
                              void* d_out, int out_size, void* d_ws, size_t ws_size,
                              hipStream_t stream)
{
    const float* x_int = (const float*)d_in[0];
    const float* x_bnd = (const float*)d_in[1];
    const float* W0 = (const float*)d_in[2];
    const float* b0 = (const float*)d_in[3];
    const float* W1 = (const float*)d_in[4];
    const float* b1 = (const float*)d_in[5];
    const float* W2 = (const float*)d_in[6];
    const float* b2 = (const float*)d_in[7];
    const float* W3 = (const float*)d_in[8];
    const float* b3 = (const float*)d_in[9];

    int NI = in_sizes[0] / 2;    // 20000
    int NB = in_sizes[1] / 2;    // 800
    int NT = NI + NB;            // 20800
    int nblk = (NT + PPB - 1) / PPB;   // 1300

    // ws: [partials 16KB][W1h 512KB][W2h 512KB]
    float* partials = (float*)d_ws;
    _Float16* W1h = (_Float16*)((char*)d_ws + 16384);
    _Float16* W2h = W1h + 262144;

    prep_wt<<<128, 256, 0, stream>>>(W1, W2, W1h, W2h);

    pois_fused<<<nblk, 512, 0, stream>>>(
        x_int, x_bnd, W0, b0, W1h, b1, W2h, b2, W3, b3,
        partials, NI, NT, nblk);

    pois_reduce<<<1, 256, 0, stream>>>(partials, (float*)d_out, nblk, NI, NB);
}